// Round 11
// baseline (3769.168 us; speedup 1.0000x reference)
//
#include <hip/hip_runtime.h>
#include <hip/hip_fp16.h>

typedef unsigned int u32;
typedef _Float16 h2v __attribute__((ext_vector_type(2)));
typedef _Float16 half8 __attribute__((ext_vector_type(8)));
typedef float f32x4 __attribute__((ext_vector_type(4)));

#define B_ 64
#define T_ 1024
#define H_ 512
#define I_ 512

__device__ __forceinline__ float dot2f(u32 w, u32 h, float acc) {
#if __has_builtin(__builtin_amdgcn_fdot2)
    return __builtin_amdgcn_fdot2(__builtin_bit_cast(h2v, w),
                                  __builtin_bit_cast(h2v, h), acc, false);
#else
    __half2 a = __builtin_bit_cast(__half2, w);
    __half2 b = __builtin_bit_cast(__half2, h);
    return acc + __low2float(a) * __low2float(b) + __high2float(a) * __high2float(b);
#endif
}

__device__ __forceinline__ u32 pkf16(float a, float b) {
    __half2 h = __floats2half2_rn(a, b);
    return __builtin_bit_cast(u32, h);
}

__device__ __forceinline__ f32x4 mfma16(uint4 a, uint4 b, f32x4 c) {
    return __builtin_amdgcn_mfma_f32_16x16x32_f16(
        __builtin_bit_cast(half8, a), __builtin_bit_cast(half8, b), c, 0, 0, 0);
}

__device__ __forceinline__ float tanh_f(float x) {
    float e = __expf(-2.f * fabsf(x));
    return __builtin_copysignf((1.f - e) / (1.f + e), x);
}

// ---------------- W_hh repack into MFMA A-fragments (ALL register-resident) ----
// 8 waves; wave w owns rows [w*64, w*64+64): 4 row-tiles (rt) x 16 k-tiles (kt).
// Frag(w,rt,kt), lane l, u32 q: A[row][k], row = w*64+rt*16+(l&15),
// k = kt*32+(l>>4)*8+2q (+1 hi half). All 64 frags/lane -> AGPRs (256 regs,
// the per-wave AGPR max; R10 proved 48 fit with VGPR_Count=128, no spill).
// Mapping HW-verified by R9/R10 PASS.
__global__ void prep_w(const float* __restrict__ Whh, u32* __restrict__ wregb) {
    const int tid = threadIdx.x;
    const int lane = tid >> 2, q = tid & 3;
    const int bid = blockIdx.x;             // bid = w*64 + kt*4 + rt
    const int w = bid >> 6, fi = bid & 63;
    const int kt = fi >> 2, rt = fi & 3;
    const int row = w * 64 + rt * 16 + (lane & 15);
    const int k0 = kt * 32 + (lane >> 4) * 8 + 2 * q;
    wregb[bid * 256 + tid] = pkf16(Whh[row * H_ + k0], Whh[row * H_ + k0 + 1]);
}

// ---------------- Phase 1: Xp = X @ W_ih^T + (b_ih + b_hh) (R4-proven) -------
#define BM 128
#define BN 64

__launch_bounds__(256, 3)
__global__ void gemm_xp(const float* __restrict__ X, const float* __restrict__ Wih,
                        const float* __restrict__ bih, const float* __restrict__ bhh,
                        float* __restrict__ out) {
    __shared__ u32 Xs[16][BM + 4];
    __shared__ u32 Ws[16][BN + 4];
    const int t = threadIdx.x;
    const int bn = blockIdx.x & 7;
    const int bm = blockIdx.x >> 3;
    const int m0 = bm * BM, n0 = bn * BN;
    const int tm = t & 15, tn = t >> 4;
    float acc[8][4];
#pragma unroll
    for (int i = 0; i < 8; i++)
#pragma unroll
        for (int j = 0; j < 4; j++) acc[i][j] = 0.f;
    const int kc = t & 7, rr = t >> 3;
    const int key = ((tm >> 2) & 1) << 2;
    for (int kt = 0; kt < 16; kt++) {
        const int k0 = kt * 32;
#pragma unroll
        for (int it = 0; it < 4; it++) {
            const int m = it * 32 + rr;
            float4 v = *(const float4*)&X[(size_t)(m0 + m) * I_ + k0 + kc * 4];
            const int mp = m ^ (((m >> 5) & 1) << 2);
            Xs[kc * 2 + 0][mp] = pkf16(v.x, v.y);
            Xs[kc * 2 + 1][mp] = pkf16(v.z, v.w);
        }
#pragma unroll
        for (int it = 0; it < 2; it++) {
            const int n = it * 32 + rr;
            float4 v = *(const float4*)&Wih[(size_t)(n0 + n) * I_ + k0 + kc * 4];
            Ws[kc * 2 + 0][n] = pkf16(v.x, v.y);
            Ws[kc * 2 + 1][n] = pkf16(v.z, v.w);
        }
        __syncthreads();
#pragma unroll
        for (int k2 = 0; k2 < 16; k2++) {
            uint4 a0 = *(const uint4*)&Xs[k2][(tm * 8) ^ key];
            uint4 a1 = *(const uint4*)&Xs[k2][(tm * 8 + 4) ^ key];
            uint4 bv = *(const uint4*)&Ws[k2][tn * 4];
            u32 aa[8] = {a0.x, a0.y, a0.z, a0.w, a1.x, a1.y, a1.z, a1.w};
            u32 bb[4] = {bv.x, bv.y, bv.z, bv.w};
#pragma unroll
            for (int mi = 0; mi < 8; mi++)
#pragma unroll
                for (int ni = 0; ni < 4; ni++)
                    acc[mi][ni] = dot2f(aa[mi], bb[ni], acc[mi][ni]);
        }
        __syncthreads();
    }
    float4 b1 = *(const float4*)&bih[n0 + tn * 4];
    float4 b2 = *(const float4*)&bhh[n0 + tn * 4];
    float4 bs = {b1.x + b2.x, b1.y + b2.y, b1.z + b2.z, b1.w + b2.w};
#pragma unroll
    for (int mi = 0; mi < 8; mi++) {
        const int row = m0 + tm * 8 + mi;
        float4 st = {acc[mi][0] + bs.x, acc[mi][1] + bs.y,
                     acc[mi][2] + bs.z, acc[mi][3] + bs.w};
        *(float4*)&out[(size_t)row * H_ + n0 + tn * 4] = st;
    }
}

// ---------------- Phase 2: MFMA scan, W fully register-resident ----------------
// 512 thr / 8 waves / waves_per_eu(2,2). Per wave per step: 64 MFMAs
// (4 rt-chains x 16 kt), A-frags from AGPRs (wf[64]), B = h broadcast to all
// 16 cols (GEMV) read from LDS: 16 ds_read_b128/lane — the ONLY LDS traffic
// (was 32/lane in R10; LDS-issue-bound at ~12cy/wave-inst).
// Tail: lane's col-group g16&3 selects its rt chain -> 4 tanh, no reduce;
// lanes g16<4 write h (global + LDS ping-pong). Raw barrier (no vmcnt drain).

#define BF(KT) (*(const uint4*)&hh[rb + (KT)*16 + hi4])
#define MFR(KT) { uint4 bf = BF(KT);                                            \
    a0 = mfma16(wf[(KT)*4+0], bf, a0); a1 = mfma16(wf[(KT)*4+1], bf, a1);       \
    a2 = mfma16(wf[(KT)*4+2], bf, a2); a3 = mfma16(wf[(KT)*4+3], bf, a3); }

__launch_bounds__(512)
__attribute__((amdgpu_waves_per_eu(2, 2)))
__global__ void rnn_scan(const u32* __restrict__ wregb, float* __restrict__ out) {
    __shared__ __align__(16) u32 hh[512];      // 2 x 512 fp16 h ping-pong
    const int tid = threadIdx.x;
    const int w = tid >> 6, lane = tid & 63;
    const int g16 = lane & 15, hi = lane >> 4, hi4 = hi * 4;
    const int gg = g16 & 3;
    const int orow = w * 64 + gg * 16 + hi4;   // this lane's 4 output rows
    const int hslot = w * 32 + gg * 8 + hi * 2;

    uint4 wf[64];                              // all 16 kt (256 regs -> AGPRs)
    const uint4* wr4 = (const uint4*)wregb;
#pragma unroll
    for (int fi = 0; fi < 64; fi++) wf[fi] = wr4[(w * 64 + fi) * 64 + lane];

    hh[tid] = 0u;                              // h0 = 0 (both buffers)
    __syncthreads();

    float* outb = out + (size_t)blockIdx.x * (T_ * H_);

#pragma unroll 1
    for (int t = 0; t < T_; t++) {
        const int rb = (t & 1) << 8;
        float4 xp = *(const float4*)&outb[(size_t)t * H_ + orow];
        f32x4 a0 = {0.f, 0.f, 0.f, 0.f}, a1 = {0.f, 0.f, 0.f, 0.f};
        f32x4 a2 = {0.f, 0.f, 0.f, 0.f}, a3 = {0.f, 0.f, 0.f, 0.f};
        MFR(0)  MFR(1)  MFR(2)  MFR(3)
        MFR(4)  MFR(5)  MFR(6)  MFR(7)
        MFR(8)  MFR(9)  MFR(10) MFR(11)
        MFR(12) MFR(13) MFR(14) MFR(15)
        // tail: select this lane's rt chain (gg), finish 4 rows
        f32x4 x0v = (gg & 1) ? a1 : a0;
        f32x4 x1v = (gg & 1) ? a3 : a2;
        f32x4 z   = (gg & 2) ? x1v : x0v;
        const float t0 = tanh_f(xp.x + z[0]);
        const float t1 = tanh_f(xp.y + z[1]);
        const float t2 = tanh_f(xp.z + z[2]);
        const float t3 = tanh_f(xp.w + z[3]);
        if (g16 < 4) {
            float4 st = {t0, t1, t2, t3};
            *(float4*)&outb[(size_t)t * H_ + orow] = st;    // h_t overwrites Xp
            uint2 ph = {pkf16(t0, t1), pkf16(t2, t3)};
            *(uint2*)&hh[(rb ^ 256) + hslot] = ph;          // h -> other buffer
        }
        asm volatile("s_waitcnt lgkmcnt(0)" ::: "memory");
        __builtin_amdgcn_sched_barrier(0);
        __builtin_amdgcn_s_barrier();
        __builtin_amdgcn_sched_barrier(0);
    }
}

extern "C" void kernel_launch(void* const* d_in, const int* in_sizes, int n_in,
                              void* d_out, int out_size, void* d_ws, size_t ws_size,
                              hipStream_t stream) {
    const float* X    = (const float*)d_in[0];
    const float* Wih  = (const float*)d_in[1];
    const float* Whh  = (const float*)d_in[2];
    const float* bih  = (const float*)d_in[3];
    const float* bhh  = (const float*)d_in[4];
    float* out = (float*)d_out;
    u32* wregb = (u32*)d_ws;    // 512 frags x 256 u32 = 512 KB

    prep_w<<<dim3(512), dim3(256), 0, stream>>>(Whh, wregb);
    gemm_xp<<<dim3((65536 / BM) * (H_ / BN)), dim3(256), 0, stream>>>(X, Wih, bih, bhh, out);
    rnn_scan<<<dim3(B_), dim3(512), 0, stream>>>(wregb, out);
}